// Round 8
// baseline (713.827 us; speedup 1.0000x reference)
//
#include <hip/hip_runtime.h>
#include <math.h>

// ---------------------------------------------------------------------------
// KGAT-HAKE, round 8: edge_att rebuilt as lane=edge (float4 row walks, zero
// cross-lane ops) + per-relation precompute of clamped mod coefficients.
// gemm/gather/scan/softmax unchanged from round 7.
// N=100000 nodes, E=1000000 edges, R=40 rels, out = N x 240 fp32.
// ---------------------------------------------------------------------------

__global__ void hist_kernel(const int* __restrict__ dst, int* __restrict__ cnt,
                            int nedges) {
    int e = blockIdx.x * blockDim.x + threadIdx.x;
    if (e < nedges) atomicAdd(&cnt[dst[e]], 1);
}

// Per-block inclusive scan of cnt -> rowptr[i+1] (block-local) + block sums.
__global__ __launch_bounds__(1024) void scan_block_kernel(
    const int* __restrict__ cnt, int* __restrict__ rowptr,
    int* __restrict__ bsum, int n) {
    __shared__ int swv[16];
    int tid = threadIdx.x, lane = tid & 63, wid = tid >> 6;
    int i = blockIdx.x * 1024 + tid;
    int v = (i < n) ? cnt[i] : 0;
    #pragma unroll
    for (int off = 1; off < 64; off <<= 1) {
        int t = __shfl_up(v, off, 64);
        if (lane >= off) v += t;
    }
    if (lane == 63) swv[wid] = v;
    __syncthreads();
    if (wid == 0) {
        int s = (lane < 16) ? swv[lane] : 0;
        #pragma unroll
        for (int off = 1; off < 16; off <<= 1) {
            int t = __shfl_up(s, off, 64);
            if (lane >= off) s += t;
        }
        if (lane < 16) swv[lane] = s;
    }
    __syncthreads();
    int offv = wid ? swv[wid - 1] : 0;
    if (i < n) rowptr[i + 1] = v + offv;
    if (tid == 1023) bsum[blockIdx.x] = v + offv;
}

// Exclusive scan of up to 128 block sums (one wave, 2 elems/lane).
__global__ __launch_bounds__(64) void scan_tops_kernel(
    const int* __restrict__ bsum, int* __restrict__ boff, int nb) {
    int l = threadIdx.x;
    int a = (2 * l < nb) ? bsum[2 * l] : 0;
    int b = (2 * l + 1 < nb) ? bsum[2 * l + 1] : 0;
    int s = a + b;
    #pragma unroll
    for (int off = 1; off < 64; off <<= 1) {
        int t = __shfl_up(s, off, 64);
        if (l >= off) s += t;
    }
    int excl = s - (a + b);
    if (2 * l < nb) boff[2 * l] = excl;
    if (2 * l + 1 < nb) boff[2 * l + 1] = excl + a;
}

__global__ __launch_bounds__(1024) void scan_add_kernel(
    int* __restrict__ rowptr, const int* __restrict__ boff, int n) {
    int i = blockIdx.x * 1024 + threadIdx.x;
    if (i < n) rowptr[i + 1] += boff[blockIdx.x];
    if (i == 0) rowptr[0] = 0;
}

// Scatter edge metadata into dst-sorted CSR slots (before scoring).
__global__ void fill_kernel(const int* __restrict__ src, const int* __restrict__ dst,
                            const int* __restrict__ etype,
                            const int* __restrict__ rowptr, int* __restrict__ cursor,
                            int* __restrict__ src_s, int* __restrict__ de_s,
                            int nedges) {
    int e = blockIdx.x * blockDim.x + threadIdx.x;
    if (e >= nedges) return;
    int d = dst[e];
    int slot = rowptr[d] + atomicAdd(&cursor[d], 1);
    src_s[slot] = src[e];
    de_s[slot] = d | (etype[e] << 20);
}

// Per-relation precompute: A=|mr|+clamp(br), B=1-clamp(br), P=pr (raw).
__global__ void rel_prep_kernel(const float* __restrict__ rel,
                                float* __restrict__ relp, int nrel) {
    int i = blockIdx.x * blockDim.x + threadIdx.x;
    if (i >= nrel * 64) return;
    int r = i >> 6, d = i & 63;
    float pr = rel[r * 192 + d];
    float mr = fabsf(rel[r * 192 + 64 + d]);
    float br = rel[r * 192 + 128 + d];
    br = fminf(br, 1.0f);
    br = fmaxf(br, -mr);          // where(br < -mr, -mr, br)
    relp[r * 192 + d]       = mr + br;     // A
    relp[r * 192 + 64 + d]  = 1.0f - br;   // B
    relp[r * 192 + 128 + d] = pr;          // P
}

// HAKE edge score, lane = edge: per-lane float4 walk of h/t/rel rows,
// register accumulation, no cross-lane ops. CSR order -> h-row L1 broadcast.
__global__ __launch_bounds__(256) void edge_att_kernel(
    const float* __restrict__ embed, const float* __restrict__ relp,
    const float* __restrict__ pw, const float* __restrict__ mw,
    const int* __restrict__ src_s, const int* __restrict__ de_s,
    float* __restrict__ att_s, int nedges)
{
    int e = blockIdx.x * blockDim.x + threadIdx.x;
    if (e >= nedges) return;
    int s = src_s[e];
    int de = de_s[e];
    int d = de & 0xFFFFF, r = de >> 20;
    const float* hrow = embed + (size_t)d * 128;
    const float* trow = embed + (size_t)s * 128;
    const float* rrow = relp + r * 192;

    // phase/2 = (ph+pr-pt) * PI/(2*EMB_RANGE); |arg| <= 3*pi/2 -> __sinf ok
    const float K = (float)(0.5 * 3.1415926235897933 / 0.21875);

    float sumsq = 0.0f, psum = 0.0f;
    #pragma unroll 2
    for (int dc = 0; dc < 64; dc += 4) {
        float4 ph4 = *(const float4*)(hrow + dc);
        float4 mh4 = *(const float4*)(hrow + 64 + dc);
        float4 pt4 = *(const float4*)(trow + dc);
        float4 mt4 = *(const float4*)(trow + 64 + dc);
        float4 A4  = *(const float4*)(rrow + dc);
        float4 B4  = *(const float4*)(rrow + 64 + dc);
        float4 P4  = *(const float4*)(rrow + 128 + dc);
        float phv[4] = {ph4.x, ph4.y, ph4.z, ph4.w};
        float mhv[4] = {mh4.x, mh4.y, mh4.z, mh4.w};
        float ptv[4] = {pt4.x, pt4.y, pt4.z, pt4.w};
        float mtv[4] = {mt4.x, mt4.y, mt4.z, mt4.w};
        float Av[4]  = {A4.x, A4.y, A4.z, A4.w};
        float Bv[4]  = {B4.x, B4.y, B4.z, B4.w};
        float Pv[4]  = {P4.x, P4.y, P4.z, P4.w};
        #pragma unroll
        for (int t = 0; t < 4; ++t) {
            float c = fmaf(mhv[t], Av[t], -(mtv[t] * Bv[t]));
            sumsq = fmaf(c, c, sumsq);
            float ph_ = (phv[t] - ptv[t]) + Pv[t];
            psum += fabsf(__sinf(ph_ * K));
        }
    }
    att_s[e] = sqrtf(sumsq) * mw[0] + psum * pw[0];
}

// Per-node softmax over dst-sorted scores (contiguous range per node).
__global__ void softmax_kernel(const int* __restrict__ rowptr,
                               float* __restrict__ att_s, int nnodes) {
    int v = blockIdx.x * blockDim.x + threadIdx.x;
    if (v >= nnodes) return;
    int beg = rowptr[v], end = rowptr[v + 1];
    if (beg == end) return;
    float m = -INFINITY;
    for (int kk = beg; kk < end; ++kk) m = fmaxf(m, att_s[kk]);
    float den = 0.0f;
    for (int kk = beg; kk < end; ++kk) {
        float ex = __expf(att_s[kk] - m);
        att_s[kk] = ex;
        den += ex;
    }
    float inv = 1.0f / den;
    for (int kk = beg; kk < end; ++kk) att_s[kk] *= inv;
}

// CSR gather: Nh[v] = sum_k a_k * node[src_k] (a_k optionally * nrm[src_k]).
// Wave per node; DIN/4 lanes per edge (float4), 4-edge-deep unroll for MLP.
template<int DIN, bool NRM>
__global__ __launch_bounds__(256) void gather_kernel(
    const float* __restrict__ node, int nstride, const float* __restrict__ nrm,
    const float* __restrict__ att_s, const int* __restrict__ src_s,
    const int* __restrict__ rowptr, float* __restrict__ Nh, int nnodes)
{
    constexpr int LPE = DIN / 4;    // lanes per edge row
    constexpr int EP  = 64 / LPE;   // edges in parallel
    constexpr int U   = 4;          // unroll depth
    int v = blockIdx.x * 4 + (threadIdx.x >> 6);
    if (v >= nnodes) return;
    int lane = threadIdx.x & 63;
    int sub = lane / LPE;
    int c = lane % LPE;
    int beg = rowptr[v];
    int deg = rowptr[v + 1] - beg;

    float4 acc = make_float4(0.f, 0.f, 0.f, 0.f);
    for (int kb = 0; kb < deg; kb += 64) {
        int kc = kb + lane;
        bool inr = kc < deg;
        int sv = inr ? src_s[beg + kc] : 0;
        float av = inr ? att_s[beg + kc] : 0.0f;
        if (NRM) av = inr ? av * nrm[sv] : 0.0f;   // fold norm at preload
        int kmax = min(64, deg - kb);
        for (int k0 = 0; k0 < kmax; k0 += U * EP) {
            float a[U];
            const float4* p[U];
            #pragma unroll
            for (int u = 0; u < U; ++u) {
                int kk = k0 + u * EP + sub;
                bool val = kk < kmax;
                int kidx = val ? kk : 0;
                int ssrc = __shfl(sv, kidx, 64);
                float aa = __shfl(av, kidx, 64);
                a[u] = val ? aa : 0.0f;
                p[u] = (const float4*)(node + (size_t)ssrc * nstride + 4 * c);
            }
            float4 rv[U];
            #pragma unroll
            for (int u = 0; u < U; ++u) rv[u] = *p[u];
            #pragma unroll
            for (int u = 0; u < U; ++u) {
                acc.x += a[u] * rv[u].x;
                acc.y += a[u] * rv[u].y;
                acc.z += a[u] * rv[u].z;
                acc.w += a[u] * rv[u].w;
            }
        }
    }
    #pragma unroll
    for (int off = LPE; off < 64; off <<= 1) {
        acc.x += __shfl_xor(acc.x, off, 64);
        acc.y += __shfl_xor(acc.y, off, 64);
        acc.z += __shfl_xor(acc.z, off, 64);
        acc.w += __shfl_xor(acc.w, off, 64);
    }
    if (sub == 0)
        *(float4*)(Nh + (size_t)v * DIN + 4 * c) = acc;
}

// Dual GEMV over a 64-node tile per 512-thread block.
// Phase 1: coalesced staging of x1=(x+Nh), x2=(x*Nh) into padded LDS.
// Phase 2: lane=node; 8 waves split j-range (jh via readfirstlane -> W loads
// are provably scalar s_load); acc = 2*DH independent FMA chains per lane.
template<int DIN, int DOUT, bool NRM>
__global__ __launch_bounds__(512) void gemm_kernel(
    const float* __restrict__ node, int nstride, const float* __restrict__ nrm_in,
    const float* __restrict__ Nh,
    const float* __restrict__ W1, const float* __restrict__ b1,
    const float* __restrict__ W2, const float* __restrict__ b2,
    float* __restrict__ out, int out_col, float* __restrict__ nrm_out, int nnodes)
{
    constexpr int XS = DIN + 1;          // padded row: lane stride 129 words
    constexpr int DH = DOUT / 8;         // j-range per wave
    __shared__ float sx1[64 * XS], sx2[64 * XS];
    __shared__ float sred[8][64];

    int tid = threadIdx.x;
    int tile0 = blockIdx.x * 64;

    // ---- phase 1: coalesced staging ----
    for (int idx = tid; idx < 64 * (DIN / 4); idx += 512) {
        int row = idx / (DIN / 4), c = idx % (DIN / 4);
        int v = tile0 + row;
        float4 nv4 = make_float4(0.f, 0.f, 0.f, 0.f);
        float4 hv4 = make_float4(0.f, 0.f, 0.f, 0.f);
        if (v < nnodes) {
            nv4 = *(const float4*)(node + (size_t)v * nstride + 4 * c);
            hv4 = *(const float4*)(Nh + (size_t)v * DIN + 4 * c);
            if (NRM) {
                float rn = nrm_in[v];
                nv4.x *= rn; nv4.y *= rn; nv4.z *= rn; nv4.w *= rn;
            }
        }
        float* p1 = sx1 + row * XS + 4 * c;
        float* p2 = sx2 + row * XS + 4 * c;
        p1[0] = nv4.x + hv4.x; p1[1] = nv4.y + hv4.y;
        p1[2] = nv4.z + hv4.z; p1[3] = nv4.w + hv4.w;
        p2[0] = nv4.x * hv4.x; p2[1] = nv4.y * hv4.y;
        p2[2] = nv4.z * hv4.z; p2[3] = nv4.w * hv4.w;
    }
    __syncthreads();

    // ---- phase 2: dual GEMV, lane = node ----
    int lane = tid & 63;
    int jh = __builtin_amdgcn_readfirstlane(tid >> 6);   // SGPR wave id
    int j0 = jh * DH;
    int v = tile0 + lane;
    bool act = v < nnodes;

    float acc1[DH], acc2[DH];
    #pragma unroll
    for (int j = 0; j < DH; ++j) { acc1[j] = 0.f; acc2[j] = 0.f; }

    const float* px1 = sx1 + lane * XS;
    const float* px2 = sx2 + lane * XS;
    #pragma unroll 1
    for (int ic = 0; ic < DIN; ic += 8) {
        float x1c[8], x2c[8];
        #pragma unroll
        for (int t = 0; t < 8; ++t) {
            x1c[t] = px1[ic + t];
            x2c[t] = px2[ic + t];
        }
        #pragma unroll
        for (int j = 0; j < DH; ++j) {
            // scalar addresses: kernel arg + SGPR j0 + loop constants -> s_load
            const float* w1 = W1 + (size_t)(j0 + j) * DIN + ic;
            const float* w2 = W2 + (size_t)(j0 + j) * DIN + ic;
            #pragma unroll
            for (int t = 0; t < 8; ++t) {
                acc1[j] = fmaf(x1c[t], w1[t], acc1[j]);
                acc2[j] = fmaf(x2c[t], w2[t], acc2[j]);
            }
        }
    }

    float o[DH];
    float ss = 0.0f;
    #pragma unroll
    for (int j = 0; j < DH; ++j) {
        float a1 = acc1[j] + b1[j0 + j];
        a1 = a1 >= 0.0f ? a1 : 0.01f * a1;   // leaky_relu
        float a2 = acc2[j] + b2[j0 + j];
        a2 = a2 >= 0.0f ? a2 : 0.01f * a2;
        o[j] = a1 + a2;
        ss += o[j] * o[j];
    }
    sred[jh][lane] = ss;
    __syncthreads();
    float tot = 0.0f;
    #pragma unroll
    for (int q = 0; q < 8; ++q) tot += sred[q][lane];
    float nv2 = fmaxf(sqrtf(tot), 1e-12f);
    float inv = 1.0f / nv2;
    if (act) {
        float* po = out + (size_t)v * 240 + out_col + j0;
        if (DH >= 4) {
            #pragma unroll
            for (int j = 0; j < DH; j += 4) {
                float4 st = make_float4(o[j] * inv, o[j + 1] * inv,
                                        o[j + 2] * inv, o[j + 3] * inv);
                *(float4*)(po + j) = st;
            }
        } else {
            #pragma unroll
            for (int j = 0; j < DH; ++j) po[j] = o[j] * inv;
        }
        if (nrm_out && jh == 0) nrm_out[v] = nv2;
    }
}

__global__ void copy_ego_kernel(const float* __restrict__ embed,
                                float* __restrict__ out, int nnodes) {
    int tid = blockIdx.x * blockDim.x + threadIdx.x;
    if (tid >= nnodes * 32) return;
    int v = tid >> 5;
    int c = tid & 31;
    float4 val = *(const float4*)(embed + (size_t)v * 128 + 4 * c);
    *(float4*)(out + (size_t)v * 240 + 4 * c) = val;
}

extern "C" void kernel_launch(void* const* d_in, const int* in_sizes, int n_in,
                              void* d_out, int out_size, void* d_ws, size_t ws_size,
                              hipStream_t stream) {
    const float* embed = (const float*)d_in[0];
    const float* rel   = (const float*)d_in[1];
    const float* pw    = (const float*)d_in[2];
    const float* mw    = (const float*)d_in[3];
    const float* W1_0  = (const float*)d_in[4];
    const float* b1_0  = (const float*)d_in[5];
    const float* W2_0  = (const float*)d_in[6];
    const float* b2_0  = (const float*)d_in[7];
    const float* W1_1  = (const float*)d_in[8];
    const float* b1_1  = (const float*)d_in[9];
    const float* W2_1  = (const float*)d_in[10];
    const float* b2_1  = (const float*)d_in[11];
    const float* W1_2  = (const float*)d_in[12];
    const float* b1_2  = (const float*)d_in[13];
    const float* W1_2b = (const float*)d_in[14];
    const float* b2_2  = (const float*)d_in[15];
    const int* src   = (const int*)d_in[16];
    const int* dst   = (const int*)d_in[17];
    const int* etype = (const int*)d_in[18];
    float* out = (float*)d_out;

    const int n = in_sizes[0] / 128;   // 100000
    const int e = in_sizes[16];        // 1000000
    const int r = in_sizes[1] / 192;   // 40

    // workspace (~65 MB), fully rewritten each call
    char* ws = (char*)d_ws;
    float* att_s  = (float*)ws;                        // E
    int*   src_s  = (int*)(att_s + e);                 // E
    int*   de_s   = src_s + e;                         // E (dst | etype<<20)
    float* Nh     = (float*)(de_s + e);                // N*128 (reused per layer)
    int*   rowptr = (int*)(Nh + (size_t)n * 128);      // N+1
    int*   cnt    = rowptr + n + 1;                    // N
    int*   cursor = cnt + n;                           // N
    int*   bsum   = cursor + n;                        // 128
    int*   boff   = bsum + 128;                        // 128
    float* nrm1   = (float*)(boff + 128);              // N
    float* nrm2   = nrm1 + n;                          // N
    float* relp   = nrm2 + n;                          // R*192

    const int NB = (n + 1023) / 1024;   // scan blocks (98)

    hipMemsetAsync(cnt, 0, (size_t)(2 * n) * 4, stream);   // cnt + cursor
    hist_kernel<<<(e + 255) / 256, 256, 0, stream>>>(dst, cnt, e);
    scan_block_kernel<<<NB, 1024, 0, stream>>>(cnt, rowptr, bsum, n);
    scan_tops_kernel<<<1, 64, 0, stream>>>(bsum, boff, NB);
    scan_add_kernel<<<NB, 1024, 0, stream>>>(rowptr, boff, n);
    fill_kernel<<<(e + 255) / 256, 256, 0, stream>>>(src, dst, etype, rowptr,
                                                     cursor, src_s, de_s, e);
    rel_prep_kernel<<<(r * 64 + 255) / 256, 256, 0, stream>>>(rel, relp, r);
    edge_att_kernel<<<(e + 255) / 256, 256, 0, stream>>>(
        embed, relp, pw, mw, src_s, de_s, att_s, e);
    softmax_kernel<<<(n + 255) / 256, 256, 0, stream>>>(rowptr, att_s, n);

    int gblocks = (n + 3) / 4;
    int tiles = (n + 63) / 64;          // 1563 node tiles (64 nodes per block)
    // ---- layer 0: 128 -> 64, out cols [128,192) ----
    gather_kernel<128, false><<<gblocks, 256, 0, stream>>>(
        embed, 128, nullptr, att_s, src_s, rowptr, Nh, n);
    gemm_kernel<128, 64, false><<<tiles, 512, 0, stream>>>(
        embed, 128, nullptr, Nh, W1_0, b1_0, W2_0, b2_0, out, 128, nrm1, n);
    // ---- layer 1: 64 -> 32, out cols [192,224) ----
    gather_kernel<64, true><<<gblocks, 256, 0, stream>>>(
        out + 128, 240, nrm1, att_s, src_s, rowptr, Nh, n);
    gemm_kernel<64, 32, true><<<tiles, 512, 0, stream>>>(
        out + 128, 240, nrm1, Nh, W1_1, b1_1, W2_1, b2_1, out, 192, nrm2, n);
    // ---- layer 2: 32 -> 16, out cols [224,240) ----
    gather_kernel<32, true><<<gblocks, 256, 0, stream>>>(
        out + 192, 240, nrm2, att_s, src_s, rowptr, Nh, n);
    gemm_kernel<32, 16, true><<<tiles, 512, 0, stream>>>(
        out + 192, 240, nrm2, Nh, W1_2, b1_2, W1_2b, b2_2, out, 224, nullptr, n);

    copy_ego_kernel<<<(n * 32 + 255) / 256, 256, 0, stream>>>(embed, out, n);
}

// Round 9
// 541.972 us; speedup vs baseline: 1.3171x; 1.3171x over previous
//
#include <hip/hip_runtime.h>
#include <math.h>

// ---------------------------------------------------------------------------
// KGAT-HAKE, round 9: fused edge-score + online-softmax + layer-0 gather
// (one wave per dst node; t-rows read ONCE, consumed in registers for both
// the HAKE score and the attention-weighted aggregation). Normalized edge
// weights for layers 1/2 produced by a tiny att_norm pass.
// N=100000 nodes, E=1000000 edges, R=40 rels, out = N x 240 fp32.
// ---------------------------------------------------------------------------

__global__ void hist_kernel(const int* __restrict__ dst, int* __restrict__ cnt,
                            int nedges) {
    int e = blockIdx.x * blockDim.x + threadIdx.x;
    if (e < nedges) atomicAdd(&cnt[dst[e]], 1);
}

// Per-block inclusive scan of cnt -> rowptr[i+1] (block-local) + block sums.
__global__ __launch_bounds__(1024) void scan_block_kernel(
    const int* __restrict__ cnt, int* __restrict__ rowptr,
    int* __restrict__ bsum, int n) {
    __shared__ int swv[16];
    int tid = threadIdx.x, lane = tid & 63, wid = tid >> 6;
    int i = blockIdx.x * 1024 + tid;
    int v = (i < n) ? cnt[i] : 0;
    #pragma unroll
    for (int off = 1; off < 64; off <<= 1) {
        int t = __shfl_up(v, off, 64);
        if (lane >= off) v += t;
    }
    if (lane == 63) swv[wid] = v;
    __syncthreads();
    if (wid == 0) {
        int s = (lane < 16) ? swv[lane] : 0;
        #pragma unroll
        for (int off = 1; off < 16; off <<= 1) {
            int t = __shfl_up(s, off, 64);
            if (lane >= off) s += t;
        }
        if (lane < 16) swv[lane] = s;
    }
    __syncthreads();
    int offv = wid ? swv[wid - 1] : 0;
    if (i < n) rowptr[i + 1] = v + offv;
    if (tid == 1023) bsum[blockIdx.x] = v + offv;
}

// Exclusive scan of up to 128 block sums (one wave, 2 elems/lane).
__global__ __launch_bounds__(64) void scan_tops_kernel(
    const int* __restrict__ bsum, int* __restrict__ boff, int nb) {
    int l = threadIdx.x;
    int a = (2 * l < nb) ? bsum[2 * l] : 0;
    int b = (2 * l + 1 < nb) ? bsum[2 * l + 1] : 0;
    int s = a + b;
    #pragma unroll
    for (int off = 1; off < 64; off <<= 1) {
        int t = __shfl_up(s, off, 64);
        if (l >= off) s += t;
    }
    int excl = s - (a + b);
    if (2 * l < nb) boff[2 * l] = excl;
    if (2 * l + 1 < nb) boff[2 * l + 1] = excl + a;
}

__global__ __launch_bounds__(1024) void scan_add_kernel(
    int* __restrict__ rowptr, const int* __restrict__ boff, int n) {
    int i = blockIdx.x * 1024 + threadIdx.x;
    if (i < n) rowptr[i + 1] += boff[blockIdx.x];
    if (i == 0) rowptr[0] = 0;
}

// Scatter edge metadata into dst-sorted CSR slots (before scoring).
__global__ void fill_kernel(const int* __restrict__ src, const int* __restrict__ dst,
                            const int* __restrict__ etype,
                            const int* __restrict__ rowptr, int* __restrict__ cursor,
                            int* __restrict__ src_s, int* __restrict__ de_s,
                            int nedges) {
    int e = blockIdx.x * blockDim.x + threadIdx.x;
    if (e >= nedges) return;
    int d = dst[e];
    int slot = rowptr[d] + atomicAdd(&cursor[d], 1);
    src_s[slot] = src[e];
    de_s[slot] = d | (etype[e] << 20);
}

// Per-relation precompute: A=|mr|+clamp(br), B=1-clamp(br), P=pr (raw).
__global__ void rel_prep_kernel(const float* __restrict__ rel,
                                float* __restrict__ relp, int nrel) {
    int i = blockIdx.x * blockDim.x + threadIdx.x;
    if (i >= nrel * 64) return;
    int r = i >> 6, d = i & 63;
    float pr = rel[r * 192 + d];
    float mr = fabsf(rel[r * 192 + 64 + d]);
    float br = rel[r * 192 + 128 + d];
    br = fminf(br, 1.0f);
    br = fmaxf(br, -mr);          // where(br < -mr, -mr, br)
    relp[r * 192 + d]       = mr + br;     // A
    relp[r * 192 + 64 + d]  = 1.0f - br;   // B
    relp[r * 192 + 128 + d] = pr;          // P
}

// Fused: per dst-node HAKE scores + online softmax + weighted gather of embed.
// One wave per node; two 32-lane subgroups process 2 edges per iteration.
// Lane (sub, c): c holds dims 4c..4c+3 (c<16 phase dims, c>=16 mod dims).
// Stores raw scores (att_s), per-node m (am) and 1/den (ai), and Nh.
__global__ __launch_bounds__(256) void att_gather_kernel(
    const float* __restrict__ embed, const float* __restrict__ relp,
    const float* __restrict__ pw, const float* __restrict__ mw,
    const int* __restrict__ src_s, const int* __restrict__ de_s,
    const int* __restrict__ rowptr,
    float* __restrict__ att_s, float* __restrict__ am, float* __restrict__ ai,
    float* __restrict__ Nh, int nnodes)
{
    int v = blockIdx.x * 4 + (threadIdx.x >> 6);
    if (v >= nnodes) return;
    int lane = threadIdx.x & 63;
    int sub = lane >> 5;          // which edge of the pair
    int c = lane & 31;            // dim-quad: dims 4c..4c+3
    int beg = rowptr[v];
    int deg = rowptr[v + 1] - beg;

    const float K = (float)(0.5 * 3.1415926235897933 / 0.21875);  // PI/(2*EMB_RANGE)
    float mwv = mw[0], pwv = pw[0];

    float4 h4 = *(const float4*)(embed + (size_t)v * 128 + 4 * c);

    float m = -INFINITY, den = 0.0f;
    float4 acc = make_float4(0.f, 0.f, 0.f, 0.f);

    for (int k0 = 0; k0 < deg; k0 += 2) {
        int ke = k0 + sub;
        bool valid = ke < deg;
        int kc = beg + (valid ? ke : 0);
        int sidx = src_s[kc];
        int r = de_s[kc] >> 20;
        float4 t4 = *(const float4*)(embed + (size_t)sidx * 128 + 4 * c);
        float pp = 0.0f, qq = 0.0f;
        if (c < 16) {
            float4 P4 = *(const float4*)(relp + r * 192 + 128 + 4 * c);
            pp  = fabsf(__sinf((h4.x + P4.x - t4.x) * K));
            pp += fabsf(__sinf((h4.y + P4.y - t4.y) * K));
            pp += fabsf(__sinf((h4.z + P4.z - t4.z) * K));
            pp += fabsf(__sinf((h4.w + P4.w - t4.w) * K));
        } else {
            float4 A4 = *(const float4*)(relp + r * 192 + 4 * (c - 16));
            float4 B4 = *(const float4*)(relp + r * 192 + 64 + 4 * (c - 16));
            float d0 = h4.x * A4.x - t4.x * B4.x;
            float d1 = h4.y * A4.y - t4.y * B4.y;
            float d2 = h4.z * A4.z - t4.z * B4.z;
            float d3 = h4.w * A4.w - t4.w * B4.w;
            qq = ((d0 * d0 + d1 * d1) + (d2 * d2 + d3 * d3));
        }
        // packed butterfly within each 32-lane subgroup: totals of pp and qq
        #pragma unroll
        for (int off = 1; off < 32; off <<= 1) {
            pp += __shfl_xor(pp, off, 64);
            qq += __shfl_xor(qq, off, 64);
        }
        float s = valid ? (sqrtf(qq) * mwv + pp * pwv) : -INFINITY;
        float so = __shfl_xor(s, 32, 64);
        float mnew = fmaxf(m, fmaxf(s, so));
        float scale = __expf(m - mnew);              // 0 on first iteration
        float w = valid ? __expf(s - mnew) : 0.0f;
        float wo = __shfl_xor(w, 32, 64);
        den = den * scale + w + wo;
        acc.x = acc.x * scale + w * t4.x;
        acc.y = acc.y * scale + w * t4.y;
        acc.z = acc.z * scale + w * t4.z;
        acc.w = acc.w * scale + w * t4.w;
        if (valid && c == 0) att_s[kc] = s;          // raw score
        m = mnew;
    }
    // combine the two subgroup accumulators (same dims, different edges)
    acc.x += __shfl_xor(acc.x, 32, 64);
    acc.y += __shfl_xor(acc.y, 32, 64);
    acc.z += __shfl_xor(acc.z, 32, 64);
    acc.w += __shfl_xor(acc.w, 32, 64);
    float invd = (deg > 0) ? 1.0f / den : 0.0f;
    if (sub == 0) {
        float4 o = make_float4(acc.x * invd, acc.y * invd,
                               acc.z * invd, acc.w * invd);
        *(float4*)(Nh + (size_t)v * 128 + 4 * c) = o;
        if (c == 0) { am[v] = m; ai[v] = invd; }
    }
}

// att_s[e] = exp(s - m[dst]) / den[dst]  (for layer 1/2 gathers)
__global__ void att_norm_kernel(const int* __restrict__ de_s,
                                const float* __restrict__ am,
                                const float* __restrict__ ai,
                                float* __restrict__ att_s, int nedges) {
    int e = blockIdx.x * blockDim.x + threadIdx.x;
    if (e >= nedges) return;
    int d = de_s[e] & 0xFFFFF;
    att_s[e] = __expf(att_s[e] - am[d]) * ai[d];
}

// CSR gather: Nh[v] = sum_k a_k * node[src_k] (a_k optionally * nrm[src_k]).
// Wave per node; DIN/4 lanes per edge (float4), 4-edge-deep unroll for MLP.
template<int DIN, bool NRM>
__global__ __launch_bounds__(256) void gather_kernel(
    const float* __restrict__ node, int nstride, const float* __restrict__ nrm,
    const float* __restrict__ att_s, const int* __restrict__ src_s,
    const int* __restrict__ rowptr, float* __restrict__ Nh, int nnodes)
{
    constexpr int LPE = DIN / 4;    // lanes per edge row
    constexpr int EP  = 64 / LPE;   // edges in parallel
    constexpr int U   = 4;          // unroll depth
    int v = blockIdx.x * 4 + (threadIdx.x >> 6);
    if (v >= nnodes) return;
    int lane = threadIdx.x & 63;
    int sub = lane / LPE;
    int c = lane % LPE;
    int beg = rowptr[v];
    int deg = rowptr[v + 1] - beg;

    float4 acc = make_float4(0.f, 0.f, 0.f, 0.f);
    for (int kb = 0; kb < deg; kb += 64) {
        int kc = kb + lane;
        bool inr = kc < deg;
        int sv = inr ? src_s[beg + kc] : 0;
        float av = inr ? att_s[beg + kc] : 0.0f;
        if (NRM) av = inr ? av * nrm[sv] : 0.0f;   // fold norm at preload
        int kmax = min(64, deg - kb);
        for (int k0 = 0; k0 < kmax; k0 += U * EP) {
            float a[U];
            const float4* p[U];
            #pragma unroll
            for (int u = 0; u < U; ++u) {
                int kk = k0 + u * EP + sub;
                bool val = kk < kmax;
                int kidx = val ? kk : 0;
                int ssrc = __shfl(sv, kidx, 64);
                float aa = __shfl(av, kidx, 64);
                a[u] = val ? aa : 0.0f;
                p[u] = (const float4*)(node + (size_t)ssrc * nstride + 4 * c);
            }
            float4 rv[U];
            #pragma unroll
            for (int u = 0; u < U; ++u) rv[u] = *p[u];
            #pragma unroll
            for (int u = 0; u < U; ++u) {
                acc.x += a[u] * rv[u].x;
                acc.y += a[u] * rv[u].y;
                acc.z += a[u] * rv[u].z;
                acc.w += a[u] * rv[u].w;
            }
        }
    }
    #pragma unroll
    for (int off = LPE; off < 64; off <<= 1) {
        acc.x += __shfl_xor(acc.x, off, 64);
        acc.y += __shfl_xor(acc.y, off, 64);
        acc.z += __shfl_xor(acc.z, off, 64);
        acc.w += __shfl_xor(acc.w, off, 64);
    }
    if (sub == 0)
        *(float4*)(Nh + (size_t)v * DIN + 4 * c) = acc;
}

// Dual GEMV over a 64-node tile per 512-thread block.
// Phase 1: coalesced staging of x1=(x+Nh), x2=(x*Nh) into padded LDS.
// Phase 2: lane=node; 8 waves split j-range (jh via readfirstlane -> W loads
// are provably scalar s_load); acc = 2*DH independent FMA chains per lane.
template<int DIN, int DOUT, bool NRM>
__global__ __launch_bounds__(512) void gemm_kernel(
    const float* __restrict__ node, int nstride, const float* __restrict__ nrm_in,
    const float* __restrict__ Nh,
    const float* __restrict__ W1, const float* __restrict__ b1,
    const float* __restrict__ W2, const float* __restrict__ b2,
    float* __restrict__ out, int out_col, float* __restrict__ nrm_out, int nnodes)
{
    constexpr int XS = DIN + 1;          // padded row: lane stride 129 words
    constexpr int DH = DOUT / 8;         // j-range per wave
    __shared__ float sx1[64 * XS], sx2[64 * XS];
    __shared__ float sred[8][64];

    int tid = threadIdx.x;
    int tile0 = blockIdx.x * 64;

    // ---- phase 1: coalesced staging ----
    for (int idx = tid; idx < 64 * (DIN / 4); idx += 512) {
        int row = idx / (DIN / 4), c = idx % (DIN / 4);
        int v = tile0 + row;
        float4 nv4 = make_float4(0.f, 0.f, 0.f, 0.f);
        float4 hv4 = make_float4(0.f, 0.f, 0.f, 0.f);
        if (v < nnodes) {
            nv4 = *(const float4*)(node + (size_t)v * nstride + 4 * c);
            hv4 = *(const float4*)(Nh + (size_t)v * DIN + 4 * c);
            if (NRM) {
                float rn = nrm_in[v];
                nv4.x *= rn; nv4.y *= rn; nv4.z *= rn; nv4.w *= rn;
            }
        }
        float* p1 = sx1 + row * XS + 4 * c;
        float* p2 = sx2 + row * XS + 4 * c;
        p1[0] = nv4.x + hv4.x; p1[1] = nv4.y + hv4.y;
        p1[2] = nv4.z + hv4.z; p1[3] = nv4.w + hv4.w;
        p2[0] = nv4.x * hv4.x; p2[1] = nv4.y * hv4.y;
        p2[2] = nv4.z * hv4.z; p2[3] = nv4.w * hv4.w;
    }
    __syncthreads();

    // ---- phase 2: dual GEMV, lane = node ----
    int lane = tid & 63;
    int jh = __builtin_amdgcn_readfirstlane(tid >> 6);   // SGPR wave id
    int j0 = jh * DH;
    int v = tile0 + lane;
    bool act = v < nnodes;

    float acc1[DH], acc2[DH];
    #pragma unroll
    for (int j = 0; j < DH; ++j) { acc1[j] = 0.f; acc2[j] = 0.f; }

    const float* px1 = sx1 + lane * XS;
    const float* px2 = sx2 + lane * XS;
    #pragma unroll 1
    for (int ic = 0; ic < DIN; ic += 8) {
        float x1c[8], x2c[8];
        #pragma unroll
        for (int t = 0; t < 8; ++t) {
            x1c[t] = px1[ic + t];
            x2c[t] = px2[ic + t];
        }
        #pragma unroll
        for (int j = 0; j < DH; ++j) {
            // scalar addresses: kernel arg + SGPR j0 + loop constants -> s_load
            const float* w1 = W1 + (size_t)(j0 + j) * DIN + ic;
            const float* w2 = W2 + (size_t)(j0 + j) * DIN + ic;
            #pragma unroll
            for (int t = 0; t < 8; ++t) {
                acc1[j] = fmaf(x1c[t], w1[t], acc1[j]);
                acc2[j] = fmaf(x2c[t], w2[t], acc2[j]);
            }
        }
    }

    float o[DH];
    float ss = 0.0f;
    #pragma unroll
    for (int j = 0; j < DH; ++j) {
        float a1 = acc1[j] + b1[j0 + j];
        a1 = a1 >= 0.0f ? a1 : 0.01f * a1;   // leaky_relu
        float a2 = acc2[j] + b2[j0 + j];
        a2 = a2 >= 0.0f ? a2 : 0.01f * a2;
        o[j] = a1 + a2;
        ss += o[j] * o[j];
    }
    sred[jh][lane] = ss;
    __syncthreads();
    float tot = 0.0f;
    #pragma unroll
    for (int q = 0; q < 8; ++q) tot += sred[q][lane];
    float nv2 = fmaxf(sqrtf(tot), 1e-12f);
    float inv = 1.0f / nv2;
    if (act) {
        float* po = out + (size_t)v * 240 + out_col + j0;
        if (DH >= 4) {
            #pragma unroll
            for (int j = 0; j < DH; j += 4) {
                float4 st = make_float4(o[j] * inv, o[j + 1] * inv,
                                        o[j + 2] * inv, o[j + 3] * inv);
                *(float4*)(po + j) = st;
            }
        } else {
            #pragma unroll
            for (int j = 0; j < DH; ++j) po[j] = o[j] * inv;
        }
        if (nrm_out && jh == 0) nrm_out[v] = nv2;
    }
}

__global__ void copy_ego_kernel(const float* __restrict__ embed,
                                float* __restrict__ out, int nnodes) {
    int tid = blockIdx.x * blockDim.x + threadIdx.x;
    if (tid >= nnodes * 32) return;
    int v = tid >> 5;
    int c = tid & 31;
    float4 val = *(const float4*)(embed + (size_t)v * 128 + 4 * c);
    *(float4*)(out + (size_t)v * 240 + 4 * c) = val;
}

extern "C" void kernel_launch(void* const* d_in, const int* in_sizes, int n_in,
                              void* d_out, int out_size, void* d_ws, size_t ws_size,
                              hipStream_t stream) {
    const float* embed = (const float*)d_in[0];
    const float* rel   = (const float*)d_in[1];
    const float* pw    = (const float*)d_in[2];
    const float* mw    = (const float*)d_in[3];
    const float* W1_0  = (const float*)d_in[4];
    const float* b1_0  = (const float*)d_in[5];
    const float* W2_0  = (const float*)d_in[6];
    const float* b2_0  = (const float*)d_in[7];
    const float* W1_1  = (const float*)d_in[8];
    const float* b1_1  = (const float*)d_in[9];
    const float* W2_1  = (const float*)d_in[10];
    const float* b2_1  = (const float*)d_in[11];
    const float* W1_2  = (const float*)d_in[12];
    const float* b1_2  = (const float*)d_in[13];
    const float* W1_2b = (const float*)d_in[14];
    const float* b2_2  = (const float*)d_in[15];
    const int* src   = (const int*)d_in[16];
    const int* dst   = (const int*)d_in[17];
    const int* etype = (const int*)d_in[18];
    float* out = (float*)d_out;

    const int n = in_sizes[0] / 128;   // 100000
    const int e = in_sizes[16];        // 1000000
    const int r = in_sizes[1] / 192;   // 40

    // workspace (~66 MB), fully rewritten each call
    char* ws = (char*)d_ws;
    float* att_s  = (float*)ws;                        // E
    int*   src_s  = (int*)(att_s + e);                 // E
    int*   de_s   = src_s + e;                         // E (dst | etype<<20)
    float* Nh     = (float*)(de_s + e);                // N*128 (reused per layer)
    int*   rowptr = (int*)(Nh + (size_t)n * 128);      // N+1
    int*   cnt    = rowptr + n + 1;                    // N
    int*   cursor = cnt + n;                           // N
    int*   bsum   = cursor + n;                        // 128
    int*   boff   = bsum + 128;                        // 128
    float* nrm1   = (float*)(boff + 128);              // N
    float* nrm2   = nrm1 + n;                          // N
    float* relp   = nrm2 + n;                          // R*192
    float* am     = relp + r * 192;                    // N (softmax max)
    float* ai     = am + n;                            // N (1/den)

    const int NB = (n + 1023) / 1024;   // scan blocks (98)

    hipMemsetAsync(cnt, 0, (size_t)(2 * n) * 4, stream);   // cnt + cursor
    hist_kernel<<<(e + 255) / 256, 256, 0, stream>>>(dst, cnt, e);
    scan_block_kernel<<<NB, 1024, 0, stream>>>(cnt, rowptr, bsum, n);
    scan_tops_kernel<<<1, 64, 0, stream>>>(bsum, boff, NB);
    scan_add_kernel<<<NB, 1024, 0, stream>>>(rowptr, boff, n);
    fill_kernel<<<(e + 255) / 256, 256, 0, stream>>>(src, dst, etype, rowptr,
                                                     cursor, src_s, de_s, e);
    rel_prep_kernel<<<(r * 64 + 255) / 256, 256, 0, stream>>>(rel, relp, r);

    int gblocks = (n + 3) / 4;
    int tiles = (n + 63) / 64;          // 1563 node tiles (64 nodes per block)

    // ---- fused: scores + online softmax + layer-0 gather ----
    att_gather_kernel<<<gblocks, 256, 0, stream>>>(
        embed, relp, pw, mw, src_s, de_s, rowptr, att_s, am, ai, Nh, n);
    att_norm_kernel<<<(e + 255) / 256, 256, 0, stream>>>(de_s, am, ai, att_s, e);

    // ---- layer 0: 128 -> 64, out cols [128,192) ----
    gemm_kernel<128, 64, false><<<tiles, 512, 0, stream>>>(
        embed, 128, nullptr, Nh, W1_0, b1_0, W2_0, b2_0, out, 128, nrm1, n);
    // ---- layer 1: 64 -> 32, out cols [192,224) ----
    gather_kernel<64, true><<<gblocks, 256, 0, stream>>>(
        out + 128, 240, nrm1, att_s, src_s, rowptr, Nh, n);
    gemm_kernel<64, 32, true><<<tiles, 512, 0, stream>>>(
        out + 128, 240, nrm1, Nh, W1_1, b1_1, W2_1, b2_1, out, 192, nrm2, n);
    // ---- layer 2: 32 -> 16, out cols [224,240) ----
    gather_kernel<32, true><<<gblocks, 256, 0, stream>>>(
        out + 192, 240, nrm2, att_s, src_s, rowptr, Nh, n);
    gemm_kernel<32, 16, true><<<tiles, 512, 0, stream>>>(
        out + 192, 240, nrm2, Nh, W1_2, b1_2, W1_2b, b2_2, out, 224, nullptr, n);

    copy_ego_kernel<<<(n * 32 + 255) / 256, 256, 0, stream>>>(embed, out, n);
}

// Round 10
// 517.769 us; speedup vs baseline: 1.3787x; 1.0467x over previous
//
#include <hip/hip_runtime.h>
#include <math.h>

// ---------------------------------------------------------------------------
// KGAT-HAKE, round 10: att_gather iteration slimmed — packed single-register
// butterfly (5 shuffles vs 10), NO online max (scores bounded: exp(s)<9e4,
// safe in fp32), att_s holds exp(s) and gathers fold 1/den once per node.
// Index stream packed as src|etype<<17 (one int per edge).
// N=100000 nodes, E=1000000 edges, R=40 rels, out = N x 240 fp32.
// ---------------------------------------------------------------------------

__global__ void hist_kernel(const int* __restrict__ dst, int* __restrict__ cnt,
                            int nedges) {
    int e = blockIdx.x * blockDim.x + threadIdx.x;
    if (e < nedges) atomicAdd(&cnt[dst[e]], 1);
}

// Per-block inclusive scan of cnt -> rowptr[i+1] (block-local) + block sums.
__global__ __launch_bounds__(1024) void scan_block_kernel(
    const int* __restrict__ cnt, int* __restrict__ rowptr,
    int* __restrict__ bsum, int n) {
    __shared__ int swv[16];
    int tid = threadIdx.x, lane = tid & 63, wid = tid >> 6;
    int i = blockIdx.x * 1024 + tid;
    int v = (i < n) ? cnt[i] : 0;
    #pragma unroll
    for (int off = 1; off < 64; off <<= 1) {
        int t = __shfl_up(v, off, 64);
        if (lane >= off) v += t;
    }
    if (lane == 63) swv[wid] = v;
    __syncthreads();
    if (wid == 0) {
        int s = (lane < 16) ? swv[lane] : 0;
        #pragma unroll
        for (int off = 1; off < 16; off <<= 1) {
            int t = __shfl_up(s, off, 64);
            if (lane >= off) s += t;
        }
        if (lane < 16) swv[lane] = s;
    }
    __syncthreads();
    int offv = wid ? swv[wid - 1] : 0;
    if (i < n) rowptr[i + 1] = v + offv;
    if (tid == 1023) bsum[blockIdx.x] = v + offv;
}

// Exclusive scan of up to 128 block sums (one wave, 2 elems/lane).
__global__ __launch_bounds__(64) void scan_tops_kernel(
    const int* __restrict__ bsum, int* __restrict__ boff, int nb) {
    int l = threadIdx.x;
    int a = (2 * l < nb) ? bsum[2 * l] : 0;
    int b = (2 * l + 1 < nb) ? bsum[2 * l + 1] : 0;
    int s = a + b;
    #pragma unroll
    for (int off = 1; off < 64; off <<= 1) {
        int t = __shfl_up(s, off, 64);
        if (l >= off) s += t;
    }
    int excl = s - (a + b);
    if (2 * l < nb) boff[2 * l] = excl;
    if (2 * l + 1 < nb) boff[2 * l + 1] = excl + a;
}

__global__ __launch_bounds__(1024) void scan_add_kernel(
    int* __restrict__ rowptr, const int* __restrict__ boff, int n) {
    int i = blockIdx.x * 1024 + threadIdx.x;
    if (i < n) rowptr[i + 1] += boff[blockIdx.x];
    if (i == 0) rowptr[0] = 0;
}

// Scatter packed src|etype<<17 into dst-sorted CSR slots.
__global__ void fill_kernel(const int* __restrict__ src, const int* __restrict__ dst,
                            const int* __restrict__ etype,
                            const int* __restrict__ rowptr, int* __restrict__ cursor,
                            int* __restrict__ se_s, int nedges) {
    int e = blockIdx.x * blockDim.x + threadIdx.x;
    if (e >= nedges) return;
    int d = dst[e];
    int slot = rowptr[d] + atomicAdd(&cursor[d], 1);
    se_s[slot] = src[e] | (etype[e] << 17);
}

// Per-relation precompute: A=|mr|+clamp(br), B=1-clamp(br), P=pr (raw).
__global__ void rel_prep_kernel(const float* __restrict__ rel,
                                float* __restrict__ relp, int nrel) {
    int i = blockIdx.x * blockDim.x + threadIdx.x;
    if (i >= nrel * 64) return;
    int r = i >> 6, d = i & 63;
    float pr = rel[r * 192 + d];
    float mr = fabsf(rel[r * 192 + 64 + d]);
    float br = rel[r * 192 + 128 + d];
    br = fminf(br, 1.0f);
    br = fmaxf(br, -mr);          // where(br < -mr, -mr, br)
    relp[r * 192 + d]       = mr + br;     // A
    relp[r * 192 + 64 + d]  = 1.0f - br;   // B
    relp[r * 192 + 128 + d] = pr;          // P
}

// Fused: HAKE scores + softmax accumulation + layer-0 gather, wave per node.
// Two 32-lane subgroups = 2 edges/iter; lane c<16 computes 4 phase dims,
// c>=16 computes 4 mod dims. Single-register butterfly (offsets 1..8), one
// half-swap shuffle, w=exp(s) (no max: s bounded ~[0,11.4]), acc += w*t4.
// Stores w into att_s; ai[v] = 1/den; Nh[v] = acc/den.
__global__ __launch_bounds__(256) void att_gather_kernel(
    const float* __restrict__ embed, const float* __restrict__ relp,
    const float* __restrict__ pw, const float* __restrict__ mw,
    const int* __restrict__ se_s, const int* __restrict__ rowptr,
    float* __restrict__ att_s, float* __restrict__ ai,
    float* __restrict__ Nh, int nnodes)
{
    int v = blockIdx.x * 4 + (threadIdx.x >> 6);
    if (v >= nnodes) return;
    int lane = threadIdx.x & 63;
    int sub = lane >> 5;          // which edge of the pair
    int c = lane & 31;            // dim-quad within the edge
    int beg = rowptr[v];
    int deg = rowptr[v + 1] - beg;

    const float K = (float)(0.5 * 3.1415926235897933 / 0.21875);  // PI/(2*EMB_RANGE)
    float mwv = mw[0], pwv = pw[0];

    float4 h4 = *(const float4*)(embed + (size_t)v * 128 + 4 * c);

    float den = 0.0f;
    float4 acc = make_float4(0.f, 0.f, 0.f, 0.f);

    #pragma unroll 2
    for (int k0 = 0; k0 < deg; k0 += 2) {
        int ke = k0 + sub;
        bool valid = ke < deg;
        int kc = beg + (valid ? ke : 0);
        int se = se_s[kc];
        int sidx = se & 0x1FFFF;
        int r = se >> 17;
        float4 t4 = *(const float4*)(embed + (size_t)sidx * 128 + 4 * c);
        float rv;
        if (c < 16) {
            float4 P4 = *(const float4*)(relp + r * 192 + 128 + 4 * c);
            rv  = fabsf(__sinf((h4.x + P4.x - t4.x) * K));
            rv += fabsf(__sinf((h4.y + P4.y - t4.y) * K));
            rv += fabsf(__sinf((h4.z + P4.z - t4.z) * K));
            rv += fabsf(__sinf((h4.w + P4.w - t4.w) * K));
        } else {
            float4 A4 = *(const float4*)(relp + r * 192 + 4 * (c - 16));
            float4 B4 = *(const float4*)(relp + r * 192 + 64 + 4 * (c - 16));
            float d0 = h4.x * A4.x - t4.x * B4.x;
            float d1 = h4.y * A4.y - t4.y * B4.y;
            float d2 = h4.z * A4.z - t4.z * B4.z;
            float d3 = h4.w * A4.w - t4.w * B4.w;
            rv = (d0 * d0 + d1 * d1) + (d2 * d2 + d3 * d3);
        }
        // packed butterfly: offsets 1..8 stay within each 16-lane half
        #pragma unroll
        for (int off = 1; off < 16; off <<= 1)
            rv += __shfl_xor(rv, off, 64);
        float other = __shfl_xor(rv, 16, 64);   // swap pp-sum <-> qq-sum
        float ppv = (c < 16) ? rv : other;
        float qqv = (c < 16) ? other : rv;
        float s = sqrtf(qqv) * mwv + ppv * pwv;
        float w = valid ? __expf(s) : 0.0f;     // s bounded -> no max needed
        den += w;
        acc.x = fmaf(w, t4.x, acc.x);
        acc.y = fmaf(w, t4.y, acc.y);
        acc.z = fmaf(w, t4.z, acc.z);
        acc.w = fmaf(w, t4.w, acc.w);
        if (valid && c == 0) att_s[kc] = w;     // unnormalized weight
    }
    // combine the two subgroups (same dims, different edges)
    acc.x += __shfl_xor(acc.x, 32, 64);
    acc.y += __shfl_xor(acc.y, 32, 64);
    acc.z += __shfl_xor(acc.z, 32, 64);
    acc.w += __shfl_xor(acc.w, 32, 64);
    den += __shfl_xor(den, 32, 64);
    float invd = (deg > 0) ? 1.0f / den : 0.0f;
    if (sub == 0) {
        float4 o = make_float4(acc.x * invd, acc.y * invd,
                               acc.z * invd, acc.w * invd);
        *(float4*)(Nh + (size_t)v * 128 + 4 * c) = o;
        if (c == 0) ai[v] = invd;
    }
}

// CSR gather: Nh[v] = ai[v] * sum_k w_k * nrm[src_k] * node[src_k].
// Wave per node; DIN/4 lanes per edge (float4), 4-edge-deep unroll for MLP.
template<int DIN>
__global__ __launch_bounds__(256) void gather_kernel(
    const float* __restrict__ node, int nstride, const float* __restrict__ nrm,
    const float* __restrict__ att_s, const int* __restrict__ se_s,
    const int* __restrict__ rowptr, const float* __restrict__ ai,
    float* __restrict__ Nh, int nnodes)
{
    constexpr int LPE = DIN / 4;    // lanes per edge row
    constexpr int EP  = 64 / LPE;   // edges in parallel
    constexpr int U   = 4;          // unroll depth
    int v = blockIdx.x * 4 + (threadIdx.x >> 6);
    if (v >= nnodes) return;
    int lane = threadIdx.x & 63;
    int sub = lane / LPE;
    int c = lane % LPE;
    int beg = rowptr[v];
    int deg = rowptr[v + 1] - beg;

    float4 acc = make_float4(0.f, 0.f, 0.f, 0.f);
    for (int kb = 0; kb < deg; kb += 64) {
        int kc = kb + lane;
        bool inr = kc < deg;
        int sv = inr ? (se_s[beg + kc] & 0x1FFFF) : 0;
        float av = inr ? att_s[beg + kc] * nrm[sv] : 0.0f;   // fold norm
        int kmax = min(64, deg - kb);
        for (int k0 = 0; k0 < kmax; k0 += U * EP) {
            float a[U];
            const float4* p[U];
            #pragma unroll
            for (int u = 0; u < U; ++u) {
                int kk = k0 + u * EP + sub;
                bool val = kk < kmax;
                int kidx = val ? kk : 0;
                int ssrc = __shfl(sv, kidx, 64);
                float aa = __shfl(av, kidx, 64);
                a[u] = val ? aa : 0.0f;
                p[u] = (const float4*)(node + (size_t)ssrc * nstride + 4 * c);
            }
            float4 rv[U];
            #pragma unroll
            for (int u = 0; u < U; ++u) rv[u] = *p[u];
            #pragma unroll
            for (int u = 0; u < U; ++u) {
                acc.x += a[u] * rv[u].x;
                acc.y += a[u] * rv[u].y;
                acc.z += a[u] * rv[u].z;
                acc.w += a[u] * rv[u].w;
            }
        }
    }
    #pragma unroll
    for (int off = LPE; off < 64; off <<= 1) {
        acc.x += __shfl_xor(acc.x, off, 64);
        acc.y += __shfl_xor(acc.y, off, 64);
        acc.z += __shfl_xor(acc.z, off, 64);
        acc.w += __shfl_xor(acc.w, off, 64);
    }
    if (sub == 0) {
        float aiv = ai[v];                     // fold 1/den once per node
        float4 o = make_float4(acc.x * aiv, acc.y * aiv,
                               acc.z * aiv, acc.w * aiv);
        *(float4*)(Nh + (size_t)v * DIN + 4 * c) = o;
    }
}

// Dual GEMV over a 64-node tile per 512-thread block.
// Phase 1: coalesced staging of x1=(x+Nh), x2=(x*Nh) into padded LDS.
// Phase 2: lane=node; 8 waves split j-range (jh via readfirstlane -> W loads
// are provably scalar s_load); acc = 2*DH independent FMA chains per lane.
template<int DIN, int DOUT, bool NRM>
__global__ __launch_bounds__(512) void gemm_kernel(
    const float* __restrict__ node, int nstride, const float* __restrict__ nrm_in,
    const float* __restrict__ Nh,
    const float* __restrict__ W1, const float* __restrict__ b1,
    const float* __restrict__ W2, const float* __restrict__ b2,
    float* __restrict__ out, int out_col, float* __restrict__ nrm_out, int nnodes)
{
    constexpr int XS = DIN + 1;          // padded row: lane stride 129 words
    constexpr int DH = DOUT / 8;         // j-range per wave
    __shared__ float sx1[64 * XS], sx2[64 * XS];
    __shared__ float sred[8][64];

    int tid = threadIdx.x;
    int tile0 = blockIdx.x * 64;

    // ---- phase 1: coalesced staging ----
    for (int idx = tid; idx < 64 * (DIN / 4); idx += 512) {
        int row = idx / (DIN / 4), c = idx % (DIN / 4);
        int v = tile0 + row;
        float4 nv4 = make_float4(0.f, 0.f, 0.f, 0.f);
        float4 hv4 = make_float4(0.f, 0.f, 0.f, 0.f);
        if (v < nnodes) {
            nv4 = *(const float4*)(node + (size_t)v * nstride + 4 * c);
            hv4 = *(const float4*)(Nh + (size_t)v * DIN + 4 * c);
            if (NRM) {
                float rn = nrm_in[v];
                nv4.x *= rn; nv4.y *= rn; nv4.z *= rn; nv4.w *= rn;
            }
        }
        float* p1 = sx1 + row * XS + 4 * c;
        float* p2 = sx2 + row * XS + 4 * c;
        p1[0] = nv4.x + hv4.x; p1[1] = nv4.y + hv4.y;
        p1[2] = nv4.z + hv4.z; p1[3] = nv4.w + hv4.w;
        p2[0] = nv4.x * hv4.x; p2[1] = nv4.y * hv4.y;
        p2[2] = nv4.z * hv4.z; p2[3] = nv4.w * hv4.w;
    }
    __syncthreads();

    // ---- phase 2: dual GEMV, lane = node ----
    int lane = tid & 63;
    int jh = __builtin_amdgcn_readfirstlane(tid >> 6);   // SGPR wave id
    int j0 = jh * DH;
    int v = tile0 + lane;
    bool act = v < nnodes;

    float acc1[DH], acc2[DH];
    #pragma unroll
    for (int j = 0; j < DH; ++j) { acc1[j] = 0.f; acc2[j] = 0.f; }

    const float* px1 = sx1 + lane * XS;
    const float* px2 = sx2 + lane * XS;
    #pragma unroll 1
    for (int ic = 0; ic < DIN; ic += 8) {
        float x1c[8], x2c[8];
        #pragma unroll
        for (int t = 0; t < 8; ++t) {
            x1c[t] = px1[ic + t];
            x2c[t] = px2[ic + t];
        }
        #pragma unroll
        for (int j = 0; j < DH; ++j) {
            // scalar addresses: kernel arg + SGPR j0 + loop constants -> s_load
            const float* w1 = W1 + (size_t)(j0 + j) * DIN + ic;
            const float* w2 = W2 + (size_t)(j0 + j) * DIN + ic;
            #pragma unroll
            for (int t = 0; t < 8; ++t) {
                acc1[j] = fmaf(x1c[t], w1[t], acc1[j]);
                acc2[j] = fmaf(x2c[t], w2[t], acc2[j]);
            }
        }
    }

    float o[DH];
    float ss = 0.0f;
    #pragma unroll
    for (int j = 0; j < DH; ++j) {
        float a1 = acc1[j] + b1[j0 + j];
        a1 = a1 >= 0.0f ? a1 : 0.01f * a1;   // leaky_relu
        float a2 = acc2[j] + b2[j0 + j];
        a2 = a2 >= 0.0f ? a2 : 0.01f * a2;
        o[j] = a1 + a2;
        ss += o[j] * o[j];
    }
    sred[jh][lane] = ss;
    __syncthreads();
    float tot = 0.0f;
    #pragma unroll
    for (int q = 0; q < 8; ++q) tot += sred[q][lane];
    float nv2 = fmaxf(sqrtf(tot), 1e-12f);
    float inv = 1.0f / nv2;
    if (act) {
        float* po = out + (size_t)v * 240 + out_col + j0;
        if (DH >= 4) {
            #pragma unroll
            for (int j = 0; j < DH; j += 4) {
                float4 st = make_float4(o[j] * inv, o[j + 1] * inv,
                                        o[j + 2] * inv, o[j + 3] * inv);
                *(float4*)(po + j) = st;
            }
        } else {
            #pragma unroll
            for (int j = 0; j < DH; ++j) po[j] = o[j] * inv;
        }
        if (nrm_out && jh == 0) nrm_out[v] = nv2;
    }
}

__global__ void copy_ego_kernel(const float* __restrict__ embed,
                                float* __restrict__ out, int nnodes) {
    int tid = blockIdx.x * blockDim.x + threadIdx.x;
    if (tid >= nnodes * 32) return;
    int v = tid >> 5;
    int c = tid & 31;
    float4 val = *(const float4*)(embed + (size_t)v * 128 + 4 * c);
    *(float4*)(out + (size_t)v * 240 + 4 * c) = val;
}

extern "C" void kernel_launch(void* const* d_in, const int* in_sizes, int n_in,
                              void* d_out, int out_size, void* d_ws, size_t ws_size,
                              hipStream_t stream) {
    const float* embed = (const float*)d_in[0];
    const float* rel   = (const float*)d_in[1];
    const float* pw    = (const float*)d_in[2];
    const float* mw    = (const float*)d_in[3];
    const float* W1_0  = (const float*)d_in[4];
    const float* b1_0  = (const float*)d_in[5];
    const float* W2_0  = (const float*)d_in[6];
    const float* b2_0  = (const float*)d_in[7];
    const float* W1_1  = (const float*)d_in[8];
    const float* b1_1  = (const float*)d_in[9];
    const float* W2_1  = (const float*)d_in[10];
    const float* b2_1  = (const float*)d_in[11];
    const float* W1_2  = (const float*)d_in[12];
    const float* b1_2  = (const float*)d_in[13];
    const float* W1_2b = (const float*)d_in[14];
    const float* b2_2  = (const float*)d_in[15];
    const int* src   = (const int*)d_in[16];
    const int* dst   = (const int*)d_in[17];
    const int* etype = (const int*)d_in[18];
    float* out = (float*)d_out;

    const int n = in_sizes[0] / 128;   // 100000
    const int e = in_sizes[16];        // 1000000
    const int r = in_sizes[1] / 192;   // 40

    // workspace (~62 MB), fully rewritten each call
    char* ws = (char*)d_ws;
    float* att_s  = (float*)ws;                        // E (unnormalized exp(s))
    int*   se_s   = (int*)(att_s + e);                 // E (src | etype<<17)
    float* Nh     = (float*)(se_s + e);                // N*128 (reused per layer)
    int*   rowptr = (int*)(Nh + (size_t)n * 128);      // N+1
    int*   cnt    = rowptr + n + 1;                    // N
    int*   cursor = cnt + n;                           // N
    int*   bsum   = cursor + n;                        // 128
    int*   boff   = bsum + 128;                        // 128
    float* nrm1   = (float*)(boff + 128);              // N
    float* nrm2   = nrm1 + n;                          // N
    float* relp   = nrm2 + n;                          // R*192
    float* ai     = relp + r * 192;                    // N (1/den)

    const int NB = (n + 1023) / 1024;   // scan blocks (98)

    hipMemsetAsync(cnt, 0, (size_t)(2 * n) * 4, stream);   // cnt + cursor
    hist_kernel<<<(e + 255) / 256, 256, 0, stream>>>(dst, cnt, e);
    scan_block_kernel<<<NB, 1024, 0, stream>>>(cnt, rowptr, bsum, n);
    scan_tops_kernel<<<1, 64, 0, stream>>>(bsum, boff, NB);
    scan_add_kernel<<<NB, 1024, 0, stream>>>(rowptr, boff, n);
    fill_kernel<<<(e + 255) / 256, 256, 0, stream>>>(src, dst, etype, rowptr,
                                                     cursor, se_s, e);
    rel_prep_kernel<<<(r * 64 + 255) / 256, 256, 0, stream>>>(rel, relp, r);

    int gblocks = (n + 3) / 4;
    int tiles = (n + 63) / 64;          // 1563 node tiles (64 nodes per block)

    // ---- fused: scores + softmax accumulation + layer-0 gather ----
    att_gather_kernel<<<gblocks, 256, 0, stream>>>(
        embed, relp, pw, mw, se_s, rowptr, att_s, ai, Nh, n);

    // ---- layer 0: 128 -> 64, out cols [128,192) ----
    gemm_kernel<128, 64, false><<<tiles, 512, 0, stream>>>(
        embed, 128, nullptr, Nh, W1_0, b1_0, W2_0, b2_0, out, 128, nrm1, n);
    // ---- layer 1: 64 -> 32, out cols [192,224) ----
    gather_kernel<64><<<gblocks, 256, 0, stream>>>(
        out + 128, 240, nrm1, att_s, se_s, rowptr, ai, Nh, n);
    gemm_kernel<64, 32, true><<<tiles, 512, 0, stream>>>(
        out + 128, 240, nrm1, Nh, W1_1, b1_1, W2_1, b2_1, out, 192, nrm2, n);
    // ---- layer 2: 32 -> 16, out cols [224,240) ----
    gather_kernel<32><<<gblocks, 256, 0, stream>>>(
        out + 192, 240, nrm2, att_s, se_s, rowptr, ai, Nh, n);
    gemm_kernel<32, 16, true><<<tiles, 512, 0, stream>>>(
        out + 192, 240, nrm2, Nh, W1_2, b1_2, W1_2b, b2_2, out, 224, nullptr, n);

    copy_ego_kernel<<<(n * 32 + 255) / 256, 256, 0, stream>>>(embed, out, n);
}

// Round 11
// 471.868 us; speedup vs baseline: 1.5128x; 1.0973x over previous
//
#include <hip/hip_runtime.h>
#include <math.h>

// ---------------------------------------------------------------------------
// KGAT-HAKE, round 11: att_gather widened to 8 edges/iter (8 lanes/edge,
// 16 dims/lane) — 0.75 shuffles/edge, unpredicated sin path, 2.5x fewer
// iterations. copy_ego folded into gemm L0's staging phase.
// N=100000 nodes, E=1000000 edges, R=40 rels, out = N x 240 fp32.
// ---------------------------------------------------------------------------

__global__ void hist_kernel(const int* __restrict__ dst, int* __restrict__ cnt,
                            int nedges) {
    int e = blockIdx.x * blockDim.x + threadIdx.x;
    if (e < nedges) atomicAdd(&cnt[dst[e]], 1);
}

// Per-block inclusive scan of cnt -> rowptr[i+1] (block-local) + block sums.
__global__ __launch_bounds__(1024) void scan_block_kernel(
    const int* __restrict__ cnt, int* __restrict__ rowptr,
    int* __restrict__ bsum, int n) {
    __shared__ int swv[16];
    int tid = threadIdx.x, lane = tid & 63, wid = tid >> 6;
    int i = blockIdx.x * 1024 + tid;
    int v = (i < n) ? cnt[i] : 0;
    #pragma unroll
    for (int off = 1; off < 64; off <<= 1) {
        int t = __shfl_up(v, off, 64);
        if (lane >= off) v += t;
    }
    if (lane == 63) swv[wid] = v;
    __syncthreads();
    if (wid == 0) {
        int s = (lane < 16) ? swv[lane] : 0;
        #pragma unroll
        for (int off = 1; off < 16; off <<= 1) {
            int t = __shfl_up(s, off, 64);
            if (lane >= off) s += t;
        }
        if (lane < 16) swv[lane] = s;
    }
    __syncthreads();
    int offv = wid ? swv[wid - 1] : 0;
    if (i < n) rowptr[i + 1] = v + offv;
    if (tid == 1023) bsum[blockIdx.x] = v + offv;
}

// Exclusive scan of up to 128 block sums (one wave, 2 elems/lane).
__global__ __launch_bounds__(64) void scan_tops_kernel(
    const int* __restrict__ bsum, int* __restrict__ boff, int nb) {
    int l = threadIdx.x;
    int a = (2 * l < nb) ? bsum[2 * l] : 0;
    int b = (2 * l + 1 < nb) ? bsum[2 * l + 1] : 0;
    int s = a + b;
    #pragma unroll
    for (int off = 1; off < 64; off <<= 1) {
        int t = __shfl_up(s, off, 64);
        if (l >= off) s += t;
    }
    int excl = s - (a + b);
    if (2 * l < nb) boff[2 * l] = excl;
    if (2 * l + 1 < nb) boff[2 * l + 1] = excl + a;
}

__global__ __launch_bounds__(1024) void scan_add_kernel(
    int* __restrict__ rowptr, const int* __restrict__ boff, int n) {
    int i = blockIdx.x * 1024 + threadIdx.x;
    if (i < n) rowptr[i + 1] += boff[blockIdx.x];
    if (i == 0) rowptr[0] = 0;
}

// Scatter packed src|etype<<17 into dst-sorted CSR slots.
__global__ void fill_kernel(const int* __restrict__ src, const int* __restrict__ dst,
                            const int* __restrict__ etype,
                            const int* __restrict__ rowptr, int* __restrict__ cursor,
                            int* __restrict__ se_s, int nedges) {
    int e = blockIdx.x * blockDim.x + threadIdx.x;
    if (e >= nedges) return;
    int d = dst[e];
    int slot = rowptr[d] + atomicAdd(&cursor[d], 1);
    se_s[slot] = src[e] | (etype[e] << 17);
}

// Per-relation precompute: A=|mr|+clamp(br), B=1-clamp(br), P=pr (raw).
__global__ void rel_prep_kernel(const float* __restrict__ rel,
                                float* __restrict__ relp, int nrel) {
    int i = blockIdx.x * blockDim.x + threadIdx.x;
    if (i >= nrel * 64) return;
    int r = i >> 6, d = i & 63;
    float pr = rel[r * 192 + d];
    float mr = fabsf(rel[r * 192 + 64 + d]);
    float br = rel[r * 192 + 128 + d];
    br = fminf(br, 1.0f);
    br = fmaxf(br, -mr);          // where(br < -mr, -mr, br)
    relp[r * 192 + d]       = mr + br;     // A
    relp[r * 192 + 64 + d]  = 1.0f - br;   // B
    relp[r * 192 + 128 + d] = pr;          // P
}

// Fused: HAKE scores + softmax accumulation + layer-0 gather, wave per node.
// 8 edges/iter: group g=lane>>3 owns edge k0+g; lane q=lane&7 owns phase dims
// [8q,8q+8) and mod dims [64+8q,64+8q+8). Per-group reduce = shfl_xor {1,2,4};
// cross-group accumulator combine once per node via shfl_xor {8,16,32}.
// w=exp(s) (scores bounded, no max). Stores w (att_s), 1/den (ai), Nh=acc/den.
__global__ __launch_bounds__(256) void att_gather_kernel(
    const float* __restrict__ embed, const float* __restrict__ relp,
    const float* __restrict__ pw, const float* __restrict__ mw,
    const int* __restrict__ se_s, const int* __restrict__ rowptr,
    float* __restrict__ att_s, float* __restrict__ ai,
    float* __restrict__ Nh, int nnodes)
{
    int v = blockIdx.x * 4 + (threadIdx.x >> 6);
    if (v >= nnodes) return;
    int lane = threadIdx.x & 63;
    int g = lane >> 3;            // edge group
    int q = lane & 7;             // dim-slice
    int beg = rowptr[v];
    int deg = rowptr[v + 1] - beg;

    const float K = (float)(0.5 * 3.1415926235897933 / 0.21875);  // PI/(2*EMB_RANGE)
    float mwv = mw[0], pwv = pw[0];

    const float* hrow = embed + (size_t)v * 128;
    float4 hp0 = *(const float4*)(hrow + 8 * q);
    float4 hp1 = *(const float4*)(hrow + 8 * q + 4);
    float4 hm0 = *(const float4*)(hrow + 64 + 8 * q);
    float4 hm1 = *(const float4*)(hrow + 64 + 8 * q + 4);

    float den = 0.0f;
    float4 ap0 = make_float4(0.f, 0.f, 0.f, 0.f);
    float4 ap1 = make_float4(0.f, 0.f, 0.f, 0.f);
    float4 am0 = make_float4(0.f, 0.f, 0.f, 0.f);
    float4 am1 = make_float4(0.f, 0.f, 0.f, 0.f);

    for (int k0 = 0; k0 < deg; k0 += 8) {
        int ke = k0 + g;
        bool valid = ke < deg;
        int kc = beg + (valid ? ke : 0);
        int se = se_s[kc];
        int sidx = se & 0x1FFFF;
        int r = se >> 17;
        const float* trow = embed + (size_t)sidx * 128;
        float4 tp0 = *(const float4*)(trow + 8 * q);
        float4 tp1 = *(const float4*)(trow + 8 * q + 4);
        float4 tm0 = *(const float4*)(trow + 64 + 8 * q);
        float4 tm1 = *(const float4*)(trow + 64 + 8 * q + 4);
        const float* rrow = relp + r * 192;
        float4 A0 = *(const float4*)(rrow + 8 * q);
        float4 A1 = *(const float4*)(rrow + 8 * q + 4);
        float4 B0 = *(const float4*)(rrow + 64 + 8 * q);
        float4 B1 = *(const float4*)(rrow + 64 + 8 * q + 4);
        float4 P0 = *(const float4*)(rrow + 128 + 8 * q);
        float4 P1 = *(const float4*)(rrow + 128 + 8 * q + 4);

        float pp;
        pp  = fabsf(__sinf((hp0.x + P0.x - tp0.x) * K));
        pp += fabsf(__sinf((hp0.y + P0.y - tp0.y) * K));
        pp += fabsf(__sinf((hp0.z + P0.z - tp0.z) * K));
        pp += fabsf(__sinf((hp0.w + P0.w - tp0.w) * K));
        pp += fabsf(__sinf((hp1.x + P1.x - tp1.x) * K));
        pp += fabsf(__sinf((hp1.y + P1.y - tp1.y) * K));
        pp += fabsf(__sinf((hp1.z + P1.z - tp1.z) * K));
        pp += fabsf(__sinf((hp1.w + P1.w - tp1.w) * K));

        float d0 = hm0.x * A0.x - tm0.x * B0.x;
        float d1 = hm0.y * A0.y - tm0.y * B0.y;
        float d2 = hm0.z * A0.z - tm0.z * B0.z;
        float d3 = hm0.w * A0.w - tm0.w * B0.w;
        float d4 = hm1.x * A1.x - tm1.x * B1.x;
        float d5 = hm1.y * A1.y - tm1.y * B1.y;
        float d6 = hm1.z * A1.z - tm1.z * B1.z;
        float d7 = hm1.w * A1.w - tm1.w * B1.w;
        float qq = ((d0 * d0 + d1 * d1) + (d2 * d2 + d3 * d3)) +
                   ((d4 * d4 + d5 * d5) + (d6 * d6 + d7 * d7));

        // reduce pp,qq within the 8-lane group
        #pragma unroll
        for (int off = 1; off < 8; off <<= 1) {
            pp += __shfl_xor(pp, off, 64);
            qq += __shfl_xor(qq, off, 64);
        }
        float s = sqrtf(qq) * mwv + pp * pwv;
        float w = valid ? __expf(s) : 0.0f;     // s bounded -> no max needed
        den += w;
        ap0.x = fmaf(w, tp0.x, ap0.x); ap0.y = fmaf(w, tp0.y, ap0.y);
        ap0.z = fmaf(w, tp0.z, ap0.z); ap0.w = fmaf(w, tp0.w, ap0.w);
        ap1.x = fmaf(w, tp1.x, ap1.x); ap1.y = fmaf(w, tp1.y, ap1.y);
        ap1.z = fmaf(w, tp1.z, ap1.z); ap1.w = fmaf(w, tp1.w, ap1.w);
        am0.x = fmaf(w, tm0.x, am0.x); am0.y = fmaf(w, tm0.y, am0.y);
        am0.z = fmaf(w, tm0.z, am0.z); am0.w = fmaf(w, tm0.w, am0.w);
        am1.x = fmaf(w, tm1.x, am1.x); am1.y = fmaf(w, tm1.y, am1.y);
        am1.z = fmaf(w, tm1.z, am1.z); am1.w = fmaf(w, tm1.w, am1.w);
        if (valid && q == 0) att_s[kc] = w;     // 8 consecutive floats/iter
    }

    // combine the 8 groups (lane bit 3..5) for acc and den
    #pragma unroll
    for (int off = 8; off < 64; off <<= 1) {
        ap0.x += __shfl_xor(ap0.x, off, 64); ap0.y += __shfl_xor(ap0.y, off, 64);
        ap0.z += __shfl_xor(ap0.z, off, 64); ap0.w += __shfl_xor(ap0.w, off, 64);
        ap1.x += __shfl_xor(ap1.x, off, 64); ap1.y += __shfl_xor(ap1.y, off, 64);
        ap1.z += __shfl_xor(ap1.z, off, 64); ap1.w += __shfl_xor(ap1.w, off, 64);
        am0.x += __shfl_xor(am0.x, off, 64); am0.y += __shfl_xor(am0.y, off, 64);
        am0.z += __shfl_xor(am0.z, off, 64); am0.w += __shfl_xor(am0.w, off, 64);
        am1.x += __shfl_xor(am1.x, off, 64); am1.y += __shfl_xor(am1.y, off, 64);
        am1.z += __shfl_xor(am1.z, off, 64); am1.w += __shfl_xor(am1.w, off, 64);
        den += __shfl_xor(den, off, 64);
    }
    float invd = (deg > 0) ? 1.0f / den : 0.0f;
    if (g == 0) {
        float* pn = Nh + (size_t)v * 128;
        *(float4*)(pn + 8 * q) = make_float4(ap0.x * invd, ap0.y * invd,
                                             ap0.z * invd, ap0.w * invd);
        *(float4*)(pn + 8 * q + 4) = make_float4(ap1.x * invd, ap1.y * invd,
                                                 ap1.z * invd, ap1.w * invd);
        *(float4*)(pn + 64 + 8 * q) = make_float4(am0.x * invd, am0.y * invd,
                                                  am0.z * invd, am0.w * invd);
        *(float4*)(pn + 64 + 8 * q + 4) = make_float4(am1.x * invd, am1.y * invd,
                                                      am1.z * invd, am1.w * invd);
        if (q == 0) ai[v] = invd;
    }
}

// CSR gather: Nh[v] = ai[v] * sum_k w_k * nrm[src_k] * node[src_k].
// Wave per node; DIN/4 lanes per edge (float4), 4-edge-deep unroll for MLP.
template<int DIN>
__global__ __launch_bounds__(256) void gather_kernel(
    const float* __restrict__ node, int nstride, const float* __restrict__ nrm,
    const float* __restrict__ att_s, const int* __restrict__ se_s,
    const int* __restrict__ rowptr, const float* __restrict__ ai,
    float* __restrict__ Nh, int nnodes)
{
    constexpr int LPE = DIN / 4;    // lanes per edge row
    constexpr int EP  = 64 / LPE;   // edges in parallel
    constexpr int U   = 4;          // unroll depth
    int v = blockIdx.x * 4 + (threadIdx.x >> 6);
    if (v >= nnodes) return;
    int lane = threadIdx.x & 63;
    int sub = lane / LPE;
    int c = lane % LPE;
    int beg = rowptr[v];
    int deg = rowptr[v + 1] - beg;

    float4 acc = make_float4(0.f, 0.f, 0.f, 0.f);
    for (int kb = 0; kb < deg; kb += 64) {
        int kc = kb + lane;
        bool inr = kc < deg;
        int sv = inr ? (se_s[beg + kc] & 0x1FFFF) : 0;
        float av = inr ? att_s[beg + kc] * nrm[sv] : 0.0f;   // fold norm
        int kmax = min(64, deg - kb);
        for (int k0 = 0; k0 < kmax; k0 += U * EP) {
            float a[U];
            const float4* p[U];
            #pragma unroll
            for (int u = 0; u < U; ++u) {
                int kk = k0 + u * EP + sub;
                bool val = kk < kmax;
                int kidx = val ? kk : 0;
                int ssrc = __shfl(sv, kidx, 64);
                float aa = __shfl(av, kidx, 64);
                a[u] = val ? aa : 0.0f;
                p[u] = (const float4*)(node + (size_t)ssrc * nstride + 4 * c);
            }
            float4 rv[U];
            #pragma unroll
            for (int u = 0; u < U; ++u) rv[u] = *p[u];
            #pragma unroll
            for (int u = 0; u < U; ++u) {
                acc.x += a[u] * rv[u].x;
                acc.y += a[u] * rv[u].y;
                acc.z += a[u] * rv[u].z;
                acc.w += a[u] * rv[u].w;
            }
        }
    }
    #pragma unroll
    for (int off = LPE; off < 64; off <<= 1) {
        acc.x += __shfl_xor(acc.x, off, 64);
        acc.y += __shfl_xor(acc.y, off, 64);
        acc.z += __shfl_xor(acc.z, off, 64);
        acc.w += __shfl_xor(acc.w, off, 64);
    }
    if (sub == 0) {
        float aiv = ai[v];                     // fold 1/den once per node
        float4 o = make_float4(acc.x * aiv, acc.y * aiv,
                               acc.z * aiv, acc.w * aiv);
        *(float4*)(Nh + (size_t)v * DIN + 4 * c) = o;
    }
}

// Dual GEMV over a 64-node tile per 512-thread block.
// Phase 1: coalesced staging of x1=(x+Nh), x2=(x*Nh) into padded LDS; if EGO,
// also writes the raw embed row to out cols [0,DIN) (replaces copy_ego).
// Phase 2: lane=node; 8 waves split j-range (jh via readfirstlane -> W loads
// are provably scalar s_load); acc = 2*DH independent FMA chains per lane.
template<int DIN, int DOUT, bool NRM, bool EGO>
__global__ __launch_bounds__(512) void gemm_kernel(
    const float* __restrict__ node, int nstride, const float* __restrict__ nrm_in,
    const float* __restrict__ Nh,
    const float* __restrict__ W1, const float* __restrict__ b1,
    const float* __restrict__ W2, const float* __restrict__ b2,
    float* __restrict__ out, int out_col, float* __restrict__ nrm_out, int nnodes)
{
    constexpr int XS = DIN + 1;          // padded row: lane stride 129 words
    constexpr int DH = DOUT / 8;         // j-range per wave
    __shared__ float sx1[64 * XS], sx2[64 * XS];
    __shared__ float sred[8][64];

    int tid = threadIdx.x;
    int tile0 = blockIdx.x * 64;

    // ---- phase 1: coalesced staging ----
    for (int idx = tid; idx < 64 * (DIN / 4); idx += 512) {
        int row = idx / (DIN / 4), c = idx % (DIN / 4);
        int v = tile0 + row;
        float4 nv4 = make_float4(0.f, 0.f, 0.f, 0.f);
        float4 hv4 = make_float4(0.f, 0.f, 0.f, 0.f);
        if (v < nnodes) {
            nv4 = *(const float4*)(node + (size_t)v * nstride + 4 * c);
            hv4 = *(const float4*)(Nh + (size_t)v * DIN + 4 * c);
            if (EGO)
                *(float4*)(out + (size_t)v * 240 + 4 * c) = nv4;   // ego copy
            if (NRM) {
                float rn = nrm_in[v];
                nv4.x *= rn; nv4.y *= rn; nv4.z *= rn; nv4.w *= rn;
            }
        }
        float* p1 = sx1 + row * XS + 4 * c;
        float* p2 = sx2 + row * XS + 4 * c;
        p1[0] = nv4.x + hv4.x; p1[1] = nv4.y + hv4.y;
        p1[2] = nv4.z + hv4.z; p1[3] = nv4.w + hv4.w;
        p2[0] = nv4.x * hv4.x; p2[1] = nv4.y * hv4.y;
        p2[2] = nv4.z * hv4.z; p2[3] = nv4.w * hv4.w;
    }
    __syncthreads();

    // ---- phase 2: dual GEMV, lane = node ----
    int lane = tid & 63;
    int jh = __builtin_amdgcn_readfirstlane(tid >> 6);   // SGPR wave id
    int j0 = jh * DH;
    int v = tile0 + lane;
    bool act = v < nnodes;

    float acc1[DH], acc2[DH];
    #pragma unroll
    for (int j = 0; j < DH; ++j) { acc1[j] = 0.f; acc2[j] = 0.f; }

    const float* px1 = sx1 + lane * XS;
    const float* px2 = sx2 + lane * XS;
    #pragma unroll 1
    for (int ic = 0; ic < DIN; ic += 8) {
        float x1c[8], x2c[8];
        #pragma unroll
        for (int t = 0; t < 8; ++t) {
            x1c[t] = px1[ic + t];
            x2c[t] = px2[ic + t];
        }
        #pragma unroll
        for (int j = 0; j < DH; ++j) {
            // scalar addresses: kernel arg + SGPR j0 + loop constants -> s_load
            const float* w1 = W1 + (size_t)(j0 + j) * DIN + ic;
            const float* w2 = W2 + (size_t)(j0 + j) * DIN + ic;
            #pragma unroll
            for (int t = 0; t < 8; ++t) {
                acc1[j] = fmaf(x1c[t], w1[t], acc1[j]);
                acc2[j] = fmaf(x2c[t], w2[t], acc2[j]);
            }
        }
    }

    float o[DH];
    float ss = 0.0f;
    #pragma unroll
    for (int j = 0; j < DH; ++j) {
        float a1 = acc1[j] + b1[j0 + j];
        a1 = a1 >= 0.0f ? a1 : 0.01f * a1;   // leaky_relu
        float a2 = acc2[j] + b2[j0 + j];
        a2 = a2 >= 0.0f ? a2 : 0.01f * a2;
        o[j] = a1 + a2;
        ss += o[j] * o[j];
    }
    sred[jh][lane] = ss;
    __syncthreads();
    float tot = 0.0f;
    #pragma unroll
    for (int q = 0; q < 8; ++q) tot += sred[q][lane];
    float nv2 = fmaxf(sqrtf(tot), 1e-12f);
    float inv = 1.0f / nv2;
    if (act) {
        float* po = out + (size_t)v * 240 + out_col + j0;
        if (DH >= 4) {
            #pragma unroll
            for (int j = 0; j < DH; j += 4) {
                float4 st = make_float4(o[j] * inv, o[j + 1] * inv,
                                        o[j + 2] * inv, o[j + 3] * inv);
                *(float4*)(po + j) = st;
            }
        } else {
            #pragma unroll
            for (int j = 0; j < DH; ++j) po[j] = o[j] * inv;
        }
        if (nrm_out && jh == 0) nrm_out[v] = nv2;
    }
}

extern "C" void kernel_launch(void* const* d_in, const int* in_sizes, int n_in,
                              void* d_out, int out_size, void* d_ws, size_t ws_size,
                              hipStream_t stream) {
    const float* embed = (const float*)d_in[0];
    const float* rel   = (const float*)d_in[1];
    const float* pw    = (const float*)d_in[2];
    const float* mw    = (const float*)d_in[3];
    const float* W1_0  = (const float*)d_in[4];
    const float* b1_0  = (const float*)d_in[5];
    const float* W2_0  = (const float*)d_in[6];
    const float* b2_0  = (const float*)d_in[7];
    const float* W1_1  = (const float*)d_in[8];
    const float* b1_1  = (const float*)d_in[9];
    const float* W2_1  = (const float*)d_in[10];
    const float* b2_1  = (const float*)d_in[11];
    const float* W1_2  = (const float*)d_in[12];
    const float* b1_2  = (const float*)d_in[13];
    const float* W1_2b = (const float*)d_in[14];
    const float* b2_2  = (const float*)d_in[15];
    const int* src   = (const int*)d_in[16];
    const int* dst   = (const int*)d_in[17];
    const int* etype = (const int*)d_in[18];
    float* out = (float*)d_out;

    const int n = in_sizes[0] / 128;   // 100000
    const int e = in_sizes[16];        // 1000000
    const int r = in_sizes[1] / 192;   // 40

    // workspace (~62 MB), fully rewritten each call
    char* ws = (char*)d_ws;
    float* att_s  = (float*)ws;                        // E (unnormalized exp(s))
    int*   se_s   = (int*)(att_s + e);                 // E (src | etype<<17)
    float* Nh     = (float*)(se_s + e);                // N*128 (reused per layer)
    int*   rowptr = (int*)(Nh + (size_t)n * 128);      // N+1
    int*   cnt    = rowptr + n + 1;                    // N
    int*   cursor = cnt + n;                           // N
    int*   bsum   = cursor + n;                        // 128
    int*   boff   = bsum + 128;                        // 128
    float* nrm1   = (float*)(boff + 128);              // N
    float* nrm2   = nrm1 + n;                          // N
    float* relp   = nrm2 + n;                          // R*192
    float* ai     = relp + r * 192;                    // N (1/den)

    const int NB = (n + 1023) / 1024;   // scan blocks (98)

    hipMemsetAsync(cnt, 0, (size_t)(2 * n) * 4, stream);   // cnt + cursor
    hist_kernel<<<(e + 255) / 256, 256, 0, stream>>>(dst, cnt, e);
    scan_block_kernel<<<NB, 1024, 0, stream>>>(cnt, rowptr, bsum, n);
    scan_tops_kernel<<<1, 64, 0, stream>>>(bsum, boff, NB);
    scan_add_kernel<<<NB, 1024, 0, stream>>>(rowptr, boff, n);
    fill_kernel<<<(e + 255) / 256, 256, 0, stream>>>(src, dst, etype, rowptr,
                                                     cursor, se_s, e);
    rel_prep_kernel<<<(r * 64 + 255) / 256, 256, 0, stream>>>(rel, relp, r);

    int gblocks = (n + 3) / 4;
    int tiles = (n + 63) / 64;          // 1563 node tiles (64 nodes per block)

    // ---- fused: scores + softmax accumulation + layer-0 gather ----
    att_gather_kernel<<<gblocks, 256, 0, stream>>>(
        embed, relp, pw, mw, se_s, rowptr, att_s, ai, Nh, n);

    // ---- layer 0: 128 -> 64, out cols [128,192) + ego copy to cols [0,128) --
    gemm_kernel<128, 64, false, true><<<tiles, 512, 0, stream>>>(
        embed, 128, nullptr, Nh, W1_0, b1_0, W2_0, b2_0, out, 128, nrm1, n);
    // ---- layer 1: 64 -> 32, out cols [192,224) ----
    gather_kernel<64><<<gblocks, 256, 0, stream>>>(
        out + 128, 240, nrm1, att_s, se_s, rowptr, ai, Nh, n);
    gemm_kernel<64, 32, true, false><<<tiles, 512, 0, stream>>>(
        out + 128, 240, nrm1, Nh, W1_1, b1_1, W2_1, b2_1, out, 192, nrm2, n);
    // ---- layer 2: 32 -> 16, out cols [224,240) ----
    gather_kernel<32><<<gblocks, 256, 0, stream>>>(
        out + 192, 240, nrm2, att_s, se_s, rowptr, ai, Nh, n);
    gemm_kernel<32, 16, true, false><<<tiles, 512, 0, stream>>>(
        out + 192, 240, nrm2, Nh, W1_2, b1_2, W1_2b, b2_2, out, 224, nullptr, n);
}